// Round 1
// 997.434 us; speedup vs baseline: 1.1146x; 1.1146x over previous
//
#include <hip/hip_runtime.h>
#include <cmath>

#define BATCH 16
#define NROI 100
#define FLATD 10000
#define NTILE 10

typedef __attribute__((ext_vector_type(8))) short s16x8;
typedef __attribute__((ext_vector_type(4))) short s16x4;
typedef __attribute__((ext_vector_type(4))) float f32x4;

// ---------- helpers ----------
__device__ __forceinline__ float sigmoidf(float x) { return 1.0f / (1.0f + expf(-x)); }
__device__ __forceinline__ float geluf(float x) { return 0.5f * x * (1.0f + erff(x * 0.70710678118654752f)); }
__device__ __forceinline__ short f2bf(float x) {
    union { float f; unsigned u; } v; v.f = x;
    unsigned r = v.u + 0x7FFF + ((v.u >> 16) & 1);
    return (short)(r >> 16);
}

// ---------- K1: fused prep: transpose A + 4x weight transpose/convert ----------
// blocks [0,625): At; [625,1649): Wl2; [1649,2673): Wr2; [2673,2801): Wl3; [2801,2929): Wr3
__global__ __launch_bounds__(256) void prep_misc(const float* __restrict__ A, float* __restrict__ At,
                                                 const float* __restrict__ Wl2, const float* __restrict__ Wr2,
                                                 const float* __restrict__ Wl3, const float* __restrict__ Wr3,
                                                 short* __restrict__ Wt2l, short* __restrict__ Wt2r,
                                                 short* __restrict__ Wt3l, short* __restrict__ Wt3r) {
    __shared__ float t[32][33];
    int bid = blockIdx.x;
    int tid = threadIdx.x;
    if (bid < 625) {
        int e = bid * 256 + tid;
        At[e] = A[(size_t)(e & 15) * FLATD + (e >> 4)];
        return;
    }
    int r = bid - 625;
    const float* in; short* out; int N, xb, yb;
    if (r < 1024)      { in = Wl2; out = Wt2l; N = 1024; xb = r & 31; yb = r >> 5; }
    else if (r < 2048) { r -= 1024; in = Wr2; out = Wt2r; N = 1024; xb = r & 31; yb = r >> 5; }
    else if (r < 2176) { r -= 2048; in = Wl3; out = Wt3l; N = 128;  xb = r & 3;  yb = r >> 2; }
    else               { r -= 2176; in = Wr3; out = Wt3r; N = 128;  xb = r & 3;  yb = r >> 2; }
    int n0 = xb * 32, k0 = yb * 32;
    int tx = tid & 31, ty = tid >> 5;
#pragma unroll
    for (int i = 0; i < 32; i += 8)
        t[ty + i][tx] = in[(size_t)(k0 + ty + i) * N + n0 + tx];
    __syncthreads();
#pragma unroll
    for (int i = 0; i < 32; i += 8)
        out[(size_t)(n0 + ty + i) * 1024 + k0 + tx] = f2bf(t[tx][ty + i]);
}

// ---------- K2: big GEMM partials part[ky][16][10000] = A @ gbW slice (NO atomics) ----------
// grid (20 col-tiles, 25 k-splits), block 256; 2 cols/thread via float2; guarded col<10000
__global__ __launch_bounds__(256) void gemm1_part(const float* __restrict__ At, const float* __restrict__ W,
                                                  float* __restrict__ part) {
    int col = blockIdx.x * 512 + threadIdx.x * 2;
    if (col >= FLATD) return;
    int ky = blockIdx.y;
    int k0 = ky * 400, k1 = k0 + 400;
    float acc0[16], acc1[16];
#pragma unroll
    for (int m = 0; m < 16; ++m) { acc0[m] = 0.f; acc1[m] = 0.f; }
#pragma unroll 4
    for (int k = k0; k < k1; ++k) {
        float2 w = *reinterpret_cast<const float2*>(W + (size_t)k * FLATD + col);
        const float* a = At + k * 16;   // wave-uniform -> s_load
#pragma unroll
        for (int m = 0; m < 16; ++m) { acc0[m] += a[m] * w.x; acc1[m] += a[m] * w.y; }
    }
    float* dst = part + (size_t)ky * 160000;
#pragma unroll
    for (int m = 0; m < 16; ++m) {
        float2 o; o.x = acc0[m]; o.y = acc1[m];
        *reinterpret_cast<float2*>(dst + (size_t)m * FLATD + col) = o;
    }
}

// ---------- K3: fused 25-partial reduce + symmetrize + sigmoid + row stats ----------
__global__ __launch_bounds__(256) void sym_stats(const float* __restrict__ part, const float* __restrict__ gbb,
                                                 float* __restrict__ adjsym, float* __restrict__ bft) {
    __shared__ float s_adj[50][NROI + 1];
    int b = blockIdx.x;
    int i0 = blockIdx.y * 50;
    for (int idx = threadIdx.x; idx < 50 * NROI; idx += 256) {
        int ii = idx / NROI, j = idx % NROI;
        int i = i0 + ii;
        size_t e1 = (size_t)b * FLATD + i * NROI + j;
        size_t e2 = (size_t)b * FLATD + j * NROI + i;
        float s1 = 0.f, s2 = 0.f;
#pragma unroll
        for (int p = 0; p < 25; ++p) {
            s1 += part[(size_t)p * 160000 + e1];
            s2 += part[(size_t)p * 160000 + e2];
        }
        float v = 0.5f * (sigmoidf(s1 + gbb[i * NROI + j]) + sigmoidf(s2 + gbb[j * NROI + i]));
        s_adj[ii][j] = v;
        adjsym[e1] = v;
    }
    __syncthreads();
    if (threadIdx.x < 50) {
        int i = threadIdx.x;
        float sum = 0.f, sumsq = 0.f;
        for (int j = 0; j < NROI; ++j) { float v = s_adj[i][j]; sum += v; sumsq += v * v; }
        float mean = sum * 0.01f;
        float var = (sumsq - sum * sum * 0.01f) * (1.0f / 99.0f);
        var = fmaxf(var, 0.f);
        bft[(b * NROI + i0 + i) * 2 + 0] = mean;
        bft[(b * NROI + i0 + i) * 2 + 1] = sqrtf(var) + 1e-6f;
    }
}

// ---------- K4: fused quantile (blocks 0..15) + feature enhancer (blocks 16..19) ----------
// quantile: radix-select rank 7499, then tie-aware single pass for rank 7500
__global__ __launch_bounds__(512) void quant_enh(const float* __restrict__ adjsym, float* __restrict__ thr,
                                                 const float* __restrict__ bft,
                                                 const float* __restrict__ W1, const float* __restrict__ b1,
                                                 const float* __restrict__ W2, const float* __restrict__ b2,
                                                 const float* __restrict__ g, const float* __restrict__ beta,
                                                 float* __restrict__ x0) {
    if (blockIdx.x >= 16) {
        // ---- enhancer ----
        int idx = (blockIdx.x - 16) * 512 + threadIdx.x;
        if (idx >= BATCH * NROI) return;
        float f0 = bft[idx * 2 + 0], f1 = bft[idx * 2 + 1];
        float h8[8];
#pragma unroll
        for (int u = 0; u < 8; ++u) h8[u] = geluf(W1[u] * f0 + W1[8 + u] * f1 + b1[u]);
        float o[16];
        float mu = 0.f;
#pragma unroll
        for (int v = 0; v < 16; ++v) {
            float t = b2[v];
#pragma unroll
            for (int u = 0; u < 8; ++u) t += h8[u] * W2[u * 16 + v];
            o[v] = t; mu += t;
        }
        mu *= (1.0f / 16.0f);
        float var = 0.f;
#pragma unroll
        for (int v = 0; v < 16; ++v) { float d = o[v] - mu; var += d * d; }
        var *= (1.0f / 16.0f);
        float inv = rsqrtf(var + 1e-5f);
#pragma unroll
        for (int v = 0; v < 16; ++v) x0[idx * 16 + v] = (o[v] - mu) * inv * g[v] + beta[v];
        return;
    }
    // ---- quantile ----
    __shared__ int red[8];
    __shared__ float redf[8];
    int b = blockIdx.x;
    int tid = threadIdx.x;
    unsigned v[20];
    const unsigned* src = (const unsigned*)(adjsym + (size_t)b * FLATD);
#pragma unroll
    for (int s = 0; s < 20; ++s) {
        int idx = s * 512 + tid;
        v[s] = (idx < FLATD) ? src[idx] : 0x7F800000u;   // +inf pad (all vals positive, <1)
    }
    int rem = 7499;
    unsigned prefix = 0;
    for (int bit = 30; bit >= 0; --bit) {
        unsigned pshift = prefix >> (bit + 1);
        int c = 0;
#pragma unroll
        for (int s = 0; s < 20; ++s) {
            unsigned x = v[s];
            c += (((x >> (bit + 1)) == pshift) && (((x >> bit) & 1u) == 0u)) ? 1 : 0;
        }
#pragma unroll
        for (int o = 32; o > 0; o >>= 1) c += __shfl_down(c, o, 64);
        if ((tid & 63) == 0) red[tid >> 6] = c;
        __syncthreads();
        int total = red[0] + red[1] + red[2] + red[3] + red[4] + red[5] + red[6] + red[7];
        __syncthreads();
        if (rem >= total) { rem -= total; prefix |= 1u << bit; }
    }
    union { unsigned u; float f; } cv; cv.u = prefix;
    float v0 = cv.f;
    // tie-aware rank-7500: count(<= v0) and min(> v0)
    int cle = 0;
    float mg = 3.4e38f;
#pragma unroll
    for (int s = 0; s < 20; ++s) {
        union { unsigned u; float f; } w; w.u = v[s];
        float f = w.f;
        cle += (f <= v0) ? 1 : 0;
        if (f > v0) mg = fminf(mg, f);
    }
#pragma unroll
    for (int o = 32; o > 0; o >>= 1) {
        cle += __shfl_down(cle, o, 64);
        mg = fminf(mg, __shfl_down(mg, o, 64));
    }
    if ((tid & 63) == 0) { red[tid >> 6] = cle; redf[tid >> 6] = mg; }
    __syncthreads();
    if (tid == 0) {
        int tc = 0; float tm = 3.4e38f;
#pragma unroll
        for (int w = 0; w < 8; ++w) { tc += red[w]; tm = fminf(tm, redf[w]); }
        float v1 = (tc >= 7501) ? v0 : tm;   // rank 7500 equals v0 if ties span the boundary
        thr[b] = v0 + 0.25f * (v1 - v0);
    }
}

// ---------- K6: fp32 tiled GEMM (layer 1, K=16), fused L/R via blockIdx.z ----------
__global__ __launch_bounds__(256) void proj_gemm(const float* __restrict__ X,
                                                 const float* __restrict__ WL, const float* __restrict__ WR,
                                                 const float* __restrict__ biasL, const float* __restrict__ biasR,
                                                 float* __restrict__ outL, float* __restrict__ outR,
                                                 int K, int Nout) {
    __shared__ float As[16][65];
    __shared__ float Bs[16][128];
    const float* W = blockIdx.z ? WR : WL;
    const float* bias = blockIdx.z ? biasR : biasL;
    float* out = blockIdx.z ? outR : outL;
    int tid = threadIdx.x;
    int tm = tid & 15, tn = tid >> 4;
    int m0 = blockIdx.x * 64, n0 = blockIdx.y * 128;
    float acc[4][8];
#pragma unroll
    for (int r = 0; r < 4; ++r)
#pragma unroll
        for (int c = 0; c < 8; ++c) acc[r][c] = 0.f;
    for (int k0 = 0; k0 < K; k0 += 16) {
        for (int e = tid; e < 64 * 16; e += 256) {
            int kk = e & 15, mm = e >> 4;
            As[kk][mm] = X[(size_t)(m0 + mm) * K + k0 + kk];
        }
        for (int e = tid; e < 16 * 128; e += 256) {
            int nn = e & 127, kk = e >> 7;
            Bs[kk][nn] = W[(size_t)(k0 + kk) * Nout + n0 + nn];
        }
        __syncthreads();
#pragma unroll
        for (int kk = 0; kk < 16; ++kk) {
            float a[4], bb[8];
#pragma unroll
            for (int r = 0; r < 4; ++r) a[r] = As[kk][tm * 4 + r];
#pragma unroll
            for (int c = 0; c < 8; ++c) bb[c] = Bs[kk][tn * 8 + c];
#pragma unroll
            for (int r = 0; r < 4; ++r)
#pragma unroll
                for (int c = 0; c < 8; ++c) acc[r][c] += a[r] * bb[c];
        }
        __syncthreads();
    }
#pragma unroll
    for (int r = 0; r < 4; ++r)
#pragma unroll
        for (int c = 0; c < 8; ++c)
            out[(size_t)(m0 + tm * 4 + r) * Nout + n0 + tn * 8 + c] = acc[r][c] + bias[n0 + tn * 8 + c];
}

// ---------- K6d: bf16 MFMA GEMM out[M,N] = Xb[M,K] @ Wt[N,K]^T + bias, BK=64 ----------
__global__ __launch_bounds__(256) void mfma_proj(const short* __restrict__ Xb,
                                                 const short* __restrict__ WtL, const short* __restrict__ WtR,
                                                 const float* __restrict__ biasL, const float* __restrict__ biasR,
                                                 float* __restrict__ outL, float* __restrict__ outR,
                                                 int K, int N) {
    __shared__ short As[64 * 72];
    __shared__ short Bs[64 * 72];
    const short* Wt  = blockIdx.z ? WtR : WtL;
    const float* bias = blockIdx.z ? biasR : biasL;
    float* out = blockIdx.z ? outR : outL;
    int m0 = blockIdx.x * 64, n0 = blockIdx.y * 64;
    int tid = threadIdx.x;
    int row = tid >> 2, part = tid & 3;
    int lane = tid & 63, wave = tid >> 6;
    int wm = wave & 1, wn = wave >> 1;
    int quad = lane >> 4, l16 = lane & 15;
    f32x4 acc00 = {}, acc01 = {}, acc10 = {}, acc11 = {};
    const short* gA = Xb + (size_t)(m0 + row) * K + part * 16;
    const short* gB = Wt + (size_t)(n0 + row) * K + part * 16;
    short* sA = As + row * 72 + part * 16;
    short* sB = Bs + row * 72 + part * 16;
    const short* fA = As + (wm * 32 + l16) * 72 + quad * 8;
    const short* fB = Bs + (wn * 32 + l16) * 72 + quad * 8;
    for (int k0 = 0; k0 < K; k0 += 64) {
        *reinterpret_cast<s16x8*>(sA)     = *reinterpret_cast<const s16x8*>(gA + k0);
        *reinterpret_cast<s16x8*>(sA + 8) = *reinterpret_cast<const s16x8*>(gA + k0 + 8);
        *reinterpret_cast<s16x8*>(sB)     = *reinterpret_cast<const s16x8*>(gB + k0);
        *reinterpret_cast<s16x8*>(sB + 8) = *reinterpret_cast<const s16x8*>(gB + k0 + 8);
        __syncthreads();
#pragma unroll
        for (int ks = 0; ks < 2; ++ks) {
            s16x8 a0 = *reinterpret_cast<const s16x8*>(fA + ks * 32);
            s16x8 a1 = *reinterpret_cast<const s16x8*>(fA + ks * 32 + 16 * 72);
            s16x8 b0 = *reinterpret_cast<const s16x8*>(fB + ks * 32);
            s16x8 b1 = *reinterpret_cast<const s16x8*>(fB + ks * 32 + 16 * 72);
            acc00 = __builtin_amdgcn_mfma_f32_16x16x32_bf16(a0, b0, acc00, 0, 0, 0);
            acc01 = __builtin_amdgcn_mfma_f32_16x16x32_bf16(a0, b1, acc01, 0, 0, 0);
            acc10 = __builtin_amdgcn_mfma_f32_16x16x32_bf16(a1, b0, acc10, 0, 0, 0);
            acc11 = __builtin_amdgcn_mfma_f32_16x16x32_bf16(a1, b1, acc11, 0, 0, 0);
        }
        __syncthreads();
    }
#pragma unroll
    for (int tm = 0; tm < 2; ++tm)
#pragma unroll
        for (int tn = 0; tn < 2; ++tn) {
            const f32x4& a = tm == 0 ? (tn == 0 ? acc00 : acc01) : (tn == 0 ? acc10 : acc11);
            int mbase = m0 + wm * 32 + tm * 16 + quad * 4;
            int n = n0 + wn * 32 + tn * 16 + l16;
            float bv = bias[n];
#pragma unroll
            for (int r = 0; r < 4; ++r)
                out[(size_t)(mbase + r) * N + n] = a[r] + bv;
        }
}

// ---------- K7: GATv2 scores + masked softmax -> alpha_T[b,h,j,i] ----------
// e = att . LeakyReLU(xl_j + xr_i) = 0.6*(dL_j + dR_i) + 0.4 * sum_c att_c*|xl+xr|
// grid (B*H, 100/NTILE), block 128 (phase A lane = j; phase B: 4 lanes per i-row)
__global__ __launch_bounds__(128) void score_softmax(const float* __restrict__ xl, const float* __restrict__ xr,
                                                     const float* __restrict__ att, const float* __restrict__ adjsym,
                                                     const float* __restrict__ thr, float* __restrict__ alpha,
                                                     int H, int C, int self_loop) {
    __shared__ float s_abs[NTILE][105];
    __shared__ float dl_lds[104];
    int bh = blockIdx.x;
    int b = bh / H, h = bh % H;
    int i0 = blockIdx.y * NTILE;
    int j = threadIdx.x;
    const float* xlrow = xl + ((size_t)(b * NROI + (j < NROI ? j : 0)) * H + h) * C;
    const float* xrbase = xr + ((size_t)(b * NROI + i0) * H + h) * C;
    const float* atth = att + h * C;
    float acc[NTILE];
    float dl = 0.f;
#pragma unroll
    for (int i = 0; i < NTILE; ++i) acc[i] = 0.f;
    for (int cc = 0; cc < C; cc += 32) {
        float xlr[32];
#pragma unroll
        for (int t = 0; t < 32; ++t) xlr[t] = xlrow[cc + t];
        const float* attp = atth + cc;            // uniform -> SGPR
#pragma unroll
        for (int t = 0; t < 32; ++t) dl += attp[t] * xlr[t];
#pragma unroll
        for (int i = 0; i < NTILE; ++i) {
            const float* xrrow = xrbase + (size_t)i * H * C + cc;   // uniform -> SGPR
            float s = 0.f;
#pragma unroll
            for (int t = 0; t < 32; ++t) s += attp[t] * fabsf(xlr[t] + xrrow[t]);
            acc[i] += s;
        }
    }
    if (j < NROI) {
        dl_lds[j] = dl;
#pragma unroll
        for (int i = 0; i < NTILE; ++i) s_abs[i][j] = acc[i];
    }
    __syncthreads();
    // ---- phase B: 4 lanes per row i ----
    int t = threadIdx.x;
    int i = t >> 2, q = t & 3;
    if (i < NTILE) {
        int gi = i0 + i;
        int c4 = C >> 2;
        const float* xrrow = xr + ((size_t)(b * NROI + gi) * H + h) * C + q * c4;
        const float* attq = atth + q * c4;
        float dr = 0.f;
        for (int c = 0; c < c4; ++c) dr += attq[c] * xrrow[c];
        dr += __shfl_xor(dr, 1, 64);
        dr += __shfl_xor(dr, 2, 64);
        float tb = thr[b];
        const float* arow = adjsym + (size_t)b * FLATD + gi * NROI + q * 25;
        float em[25];
        float mx = -3.0e38f;
#pragma unroll
        for (int k = 0; k < 25; ++k) {
            int jj = q * 25 + k;
            float e = 0.6f * (dl_lds[jj] + dr) + 0.4f * s_abs[i][jj];
            bool edge = (arow[k] > tb) || (self_loop && (jj == gi));
            float v = edge ? e : -1.0e9f;
            em[k] = v;
            mx = fmaxf(mx, v);
        }
        mx = fmaxf(mx, __shfl_xor(mx, 1, 64));
        mx = fmaxf(mx, __shfl_xor(mx, 2, 64));
        float sum = 0.f;
#pragma unroll
        for (int k = 0; k < 25; ++k) {
            em[k] = (em[k] > -0.5e9f) ? expf(em[k] - mx) : 0.f;
            sum += em[k];
        }
        sum += __shfl_xor(sum, 1, 64);
        sum += __shfl_xor(sum, 2, 64);
        float inv = (sum > 0.f) ? 1.0f / sum : 0.f;   // all-masked row -> zeros (matches reference)
        float* ab = alpha + (size_t)(b * H + h) * FLATD + gi;
#pragma unroll
        for (int k = 0; k < 25; ++k) ab[(q * 25 + k) * NROI] = em[k] * inv;
    }
}

// ---------- K8: aggregation (+GELU). Non-pool path emits bf16 directly (replaces convX). ----------
__global__ __launch_bounds__(128) void agg_kernel(const float* __restrict__ xl, const float* __restrict__ alpha,
                                                  const float* __restrict__ bias, short* __restrict__ yout,
                                                  float* __restrict__ pool_out, int H, int C, int pool) {
    __shared__ float s_xl[NROI * 128];
    int bh = blockIdx.x;
    int b = bh / H, h = bh % H;
    int ch = blockIdx.y;
    int i0 = blockIdx.z * 25;
    int tid = threadIdx.x;
    for (int e = tid; e < NROI * 128; e += 128) {
        int jj = e >> 7, t = e & 127;
        s_xl[e] = xl[((size_t)(b * NROI + jj) * H + h) * C + ch * 128 + t];
    }
    __syncthreads();
    int cglob = ch * 128 + tid;
    float bval = bias[h * C + cglob];
    const float* ap = alpha + (size_t)(b * H + h) * FLATD;
    float pacc = 0.f;
    for (int ib = 0; ib < 25; ib += 8) {
        int nb = (25 - ib) >= 8 ? 8 : (25 - ib);
        float acc[8] = {0.f, 0.f, 0.f, 0.f, 0.f, 0.f, 0.f, 0.f};
        if (nb == 8) {
            for (int jj = 0; jj < NROI; ++jj) {
                float xlv = s_xl[jj * 128 + tid];
                const float* ar = ap + jj * NROI + i0 + ib;
#pragma unroll
                for (int t = 0; t < 8; ++t) acc[t] += ar[t] * xlv;
            }
        } else {
            for (int jj = 0; jj < NROI; ++jj)
                acc[0] += ap[jj * NROI + i0 + ib] * s_xl[jj * 128 + tid];
        }
        for (int t = 0; t < nb; ++t) {
            int gi = i0 + ib + t;
            float v = geluf(acc[t] + bval);
            if (pool) pacc += 0.01f * v;
            else yout[((size_t)(b * NROI + gi) * H + h) * C + cglob] = f2bf(v);
        }
    }
    if (pool) atomicAdd(pool_out + b * 128 + cglob, pacc);
}

// ---------- launcher ----------
extern "C" void kernel_launch(void* const* d_in, const int* in_sizes, int n_in,
                              void* d_out, int out_size, void* d_ws, size_t ws_size,
                              hipStream_t stream) {
    const float* A    = (const float*)d_in[0];
    const float* gbW  = (const float*)d_in[1];
    const float* gbb  = (const float*)d_in[2];
    const float* feW1 = (const float*)d_in[3];
    const float* feb1 = (const float*)d_in[4];
    const float* feW2 = (const float*)d_in[5];
    const float* feb2 = (const float*)d_in[6];
    const float* feg  = (const float*)d_in[7];
    const float* febt = (const float*)d_in[8];
    const float* Wl1  = (const float*)d_in[9];
    const float* bl1  = (const float*)d_in[10];
    const float* Wr1  = (const float*)d_in[11];
    const float* br1  = (const float*)d_in[12];
    const float* att1 = (const float*)d_in[13];
    const float* bias1= (const float*)d_in[14];
    const float* Wl2  = (const float*)d_in[15];
    const float* bl2  = (const float*)d_in[16];
    const float* Wr2  = (const float*)d_in[17];
    const float* br2  = (const float*)d_in[18];
    const float* att2 = (const float*)d_in[19];
    const float* bias2= (const float*)d_in[20];
    const float* Wl3  = (const float*)d_in[21];
    const float* bl3  = (const float*)d_in[22];
    const float* Wr3  = (const float*)d_in[23];
    const float* br3  = (const float*)d_in[24];
    const float* att3 = (const float*)d_in[25];
    const float* bias3= (const float*)d_in[26];

    float* ws = (float*)d_ws;
    float* At    = ws + 0;          // 160000
    float* adj   = ws + 160000;     // 160000
    float* thr   = ws + 320000;     // 16
    float* bft   = ws + 320016;     // 3200
    float* x0    = ws + 323216;     // 25600
    float* xlbuf = ws + 348816;     // 1638400
    float* xrbuf = ws + 1987216;    // 1638400
    float* alpha = ws + 3625616;    // 1280000
    short* Xb    = (short*)(ws + 4905616);   // 1638400 shorts = 819200 floats
    short* Wt2l  = (short*)(ws + 5724816);   // 524288 floats-worth
    short* Wt2r  = (short*)(ws + 6249104);
    short* Wt3l  = (short*)(ws + 6773392);   // 65536
    short* Wt3r  = (short*)(ws + 6838928);
    float* prep  = ws + 6904464;    // 25*160000 = 4,000,000  (end ~43.6 MB)

    hipMemsetAsync(d_out, 0, (size_t)out_size * sizeof(float), stream);

    prep_misc<<<2929, 256, 0, stream>>>(A, At, Wl2, Wr2, Wl3, Wr3, Wt2l, Wt2r, Wt3l, Wt3r);
    gemm1_part<<<dim3(20, 25), 256, 0, stream>>>(At, gbW, prep);
    sym_stats<<<dim3(BATCH, 2), 256, 0, stream>>>(prep, gbb, adj, bft);
    quant_enh<<<20, 512, 0, stream>>>(adj, thr, bft, feW1, feb1, feW2, feb2, feg, febt, x0);

    // layer 1: H=8, C=128, no self loops (K=16 -> fp32 path)
    proj_gemm<<<dim3(25, 8, 2), 256, 0, stream>>>(x0, Wl1, Wr1, bl1, br1, xlbuf, xrbuf, 16, 1024);
    score_softmax<<<dim3(128, 10), 128, 0, stream>>>(xlbuf, xrbuf, att1, adj, thr, alpha, 8, 128, 0);
    agg_kernel<<<dim3(128, 1, 4), 128, 0, stream>>>(xlbuf, alpha, bias1, Xb, nullptr, 8, 128, 0);

    // layer 2: H=4, C=256, self loops (MFMA path)
    mfma_proj<<<dim3(25, 16, 2), 256, 0, stream>>>(Xb, Wt2l, Wt2r, bl2, br2, xlbuf, xrbuf, 1024, 1024);
    score_softmax<<<dim3(64, 10), 128, 0, stream>>>(xlbuf, xrbuf, att2, adj, thr, alpha, 4, 256, 1);
    agg_kernel<<<dim3(64, 2, 4), 128, 0, stream>>>(xlbuf, alpha, bias2, Xb, nullptr, 4, 256, 0);

    // layer 3: H=1, C=128, self loops (MFMA path), mean-pool into d_out
    mfma_proj<<<dim3(25, 2, 2), 256, 0, stream>>>(Xb, Wt3l, Wt3r, bl3, br3, xlbuf, xrbuf, 1024, 128);
    score_softmax<<<dim3(16, 10), 128, 0, stream>>>(xlbuf, xrbuf, att3, adj, thr, alpha, 1, 128, 1);
    agg_kernel<<<dim3(16, 1, 4), 128, 0, stream>>>(xlbuf, alpha, bias3, nullptr, (float*)d_out, 1, 128, 1);
}

// Round 2
// 940.034 us; speedup vs baseline: 1.1827x; 1.0611x over previous
//
#include <hip/hip_runtime.h>
#include <cmath>

#define BATCH 16
#define NROI 100
#define FLATD 10000
#define NTILE 10

typedef __attribute__((ext_vector_type(8))) short s16x8;
typedef __attribute__((ext_vector_type(4))) short s16x4;
typedef __attribute__((ext_vector_type(4))) float f32x4;

// ---------- helpers ----------
__device__ __forceinline__ float sigmoidf(float x) { return 1.0f / (1.0f + expf(-x)); }
__device__ __forceinline__ float geluf(float x) { return 0.5f * x * (1.0f + erff(x * 0.70710678118654752f)); }
__device__ __forceinline__ short f2bf(float x) {
    union { float f; unsigned u; } v; v.f = x;
    unsigned r = v.u + 0x7FFF + ((v.u >> 16) & 1);
    return (short)(r >> 16);
}

// ---------- K1: weight transpose/convert fp32 [K,N] -> bf16 [N,K] ----------
// blocks [0,1024): Wl2; [1024,2048): Wr2; [2048,2176): Wl3; [2176,2304): Wr3
__global__ __launch_bounds__(256) void prep_w(const float* __restrict__ Wl2, const float* __restrict__ Wr2,
                                              const float* __restrict__ Wl3, const float* __restrict__ Wr3,
                                              short* __restrict__ Wt2l, short* __restrict__ Wt2r,
                                              short* __restrict__ Wt3l, short* __restrict__ Wt3r) {
    __shared__ float t[32][33];
    int r = blockIdx.x;
    int tid = threadIdx.x;
    const float* in; short* out; int N, xb, yb;
    if (r < 1024)      { in = Wl2; out = Wt2l; N = 1024; xb = r & 31; yb = r >> 5; }
    else if (r < 2048) { r -= 1024; in = Wr2; out = Wt2r; N = 1024; xb = r & 31; yb = r >> 5; }
    else if (r < 2176) { r -= 2048; in = Wl3; out = Wt3l; N = 128;  xb = r & 3;  yb = r >> 2; }
    else               { r -= 2176; in = Wr3; out = Wt3r; N = 128;  xb = r & 3;  yb = r >> 2; }
    int n0 = xb * 32, k0 = yb * 32;
    int tx = tid & 31, ty = tid >> 5;
#pragma unroll
    for (int i = 0; i < 32; i += 8)
        t[ty + i][tx] = in[(size_t)(k0 + ty + i) * N + n0 + tx];
    __syncthreads();
#pragma unroll
    for (int i = 0; i < 32; i += 8)
        out[(size_t)(n0 + ty + i) * 1024 + k0 + tx] = f2bf(t[tx][ty + i]);
}

// ---------- K2: big GEMM partials part[ky][16][10000] = A @ gbW slice ----------
// grid (20 col-tiles, 25 k-splits), block 256; A k-slice staged in LDS (no At dependency)
__global__ __launch_bounds__(256) void gemm1_part(const float* __restrict__ A, const float* __restrict__ W,
                                                  float* __restrict__ part) {
    __shared__ float sA[400][16];
    int ky = blockIdx.y;
    int k0 = ky * 400;
    int tid = threadIdx.x;
    for (int e = tid; e < 16 * 400; e += 256) {
        int m = e / 400, kk = e - m * 400;
        sA[kk][m] = A[(size_t)m * FLATD + k0 + kk];   // coalesced read (kk fastest)
    }
    __syncthreads();
    int col = blockIdx.x * 512 + tid * 2;
    if (col >= FLATD) return;
    float acc0[16], acc1[16];
#pragma unroll
    for (int m = 0; m < 16; ++m) { acc0[m] = 0.f; acc1[m] = 0.f; }
#pragma unroll 4
    for (int kk = 0; kk < 400; ++kk) {
        float2 w = *reinterpret_cast<const float2*>(W + (size_t)(k0 + kk) * FLATD + col);
        const float* a = sA[kk];                      // broadcast ds_read_b128 x4
#pragma unroll
        for (int m = 0; m < 16; ++m) { acc0[m] += a[m] * w.x; acc1[m] += a[m] * w.y; }
    }
    float* dst = part + (size_t)ky * 160000;
#pragma unroll
    for (int m = 0; m < 16; ++m) {
        float2 o; o.x = acc0[m]; o.y = acc1[m];
        *reinterpret_cast<float2*>(dst + (size_t)m * FLATD + col) = o;
    }
}

// ---------- K3: fused 25-partial reduce + symmetrize + sigmoid + row stats ----------
__global__ __launch_bounds__(256) void sym_stats(const float* __restrict__ part, const float* __restrict__ gbb,
                                                 float* __restrict__ adjsym, float* __restrict__ bft) {
    __shared__ float s_adj[50][NROI + 1];
    int b = blockIdx.x;
    int i0 = blockIdx.y * 50;
    for (int idx = threadIdx.x; idx < 50 * NROI; idx += 256) {
        int ii = idx / NROI, j = idx % NROI;
        int i = i0 + ii;
        size_t e1 = (size_t)b * FLATD + i * NROI + j;
        size_t e2 = (size_t)b * FLATD + j * NROI + i;
        float s1 = 0.f, s2 = 0.f;
#pragma unroll
        for (int p = 0; p < 25; ++p) {
            s1 += part[(size_t)p * 160000 + e1];
            s2 += part[(size_t)p * 160000 + e2];
        }
        float v = 0.5f * (sigmoidf(s1 + gbb[i * NROI + j]) + sigmoidf(s2 + gbb[j * NROI + i]));
        s_adj[ii][j] = v;
        adjsym[e1] = v;
    }
    __syncthreads();
    if (threadIdx.x < 50) {
        int i = threadIdx.x;
        float sum = 0.f, sumsq = 0.f;
        for (int j = 0; j < NROI; ++j) { float v = s_adj[i][j]; sum += v; sumsq += v * v; }
        float mean = sum * 0.01f;
        float var = (sumsq - sum * sum * 0.01f) * (1.0f / 99.0f);
        var = fmaxf(var, 0.f);
        bft[(b * NROI + i0 + i) * 2 + 0] = mean;
        bft[(b * NROI + i0 + i) * 2 + 1] = sqrtf(var) + 1e-6f;
    }
}

// ---------- K4: fused quantile (blocks 0..15) + feature enhancer (blocks 16..19) ----------
__global__ __launch_bounds__(512) void quant_enh(const float* __restrict__ adjsym, float* __restrict__ thr,
                                                 const float* __restrict__ bft,
                                                 const float* __restrict__ W1, const float* __restrict__ b1,
                                                 const float* __restrict__ W2, const float* __restrict__ b2,
                                                 const float* __restrict__ g, const float* __restrict__ beta,
                                                 float* __restrict__ x0) {
    if (blockIdx.x >= 16) {
        int idx = (blockIdx.x - 16) * 512 + threadIdx.x;
        if (idx >= BATCH * NROI) return;
        float f0 = bft[idx * 2 + 0], f1 = bft[idx * 2 + 1];
        float h8[8];
#pragma unroll
        for (int u = 0; u < 8; ++u) h8[u] = geluf(W1[u] * f0 + W1[8 + u] * f1 + b1[u]);
        float o[16];
        float mu = 0.f;
#pragma unroll
        for (int v = 0; v < 16; ++v) {
            float t = b2[v];
#pragma unroll
            for (int u = 0; u < 8; ++u) t += h8[u] * W2[u * 16 + v];
            o[v] = t; mu += t;
        }
        mu *= (1.0f / 16.0f);
        float var = 0.f;
#pragma unroll
        for (int v = 0; v < 16; ++v) { float d = o[v] - mu; var += d * d; }
        var *= (1.0f / 16.0f);
        float inv = rsqrtf(var + 1e-5f);
#pragma unroll
        for (int v = 0; v < 16; ++v) x0[idx * 16 + v] = (o[v] - mu) * inv * g[v] + beta[v];
        return;
    }
    __shared__ int red[8];
    __shared__ float redf[8];
    int b = blockIdx.x;
    int tid = threadIdx.x;
    unsigned v[20];
    const unsigned* src = (const unsigned*)(adjsym + (size_t)b * FLATD);
#pragma unroll
    for (int s = 0; s < 20; ++s) {
        int idx = s * 512 + tid;
        v[s] = (idx < FLATD) ? src[idx] : 0x7F800000u;
    }
    int rem = 7499;
    unsigned prefix = 0;
    for (int bit = 30; bit >= 0; --bit) {
        unsigned pshift = prefix >> (bit + 1);
        int c = 0;
#pragma unroll
        for (int s = 0; s < 20; ++s) {
            unsigned x = v[s];
            c += (((x >> (bit + 1)) == pshift) && (((x >> bit) & 1u) == 0u)) ? 1 : 0;
        }
#pragma unroll
        for (int o = 32; o > 0; o >>= 1) c += __shfl_down(c, o, 64);
        if ((tid & 63) == 0) red[tid >> 6] = c;
        __syncthreads();
        int total = red[0] + red[1] + red[2] + red[3] + red[4] + red[5] + red[6] + red[7];
        __syncthreads();
        if (rem >= total) { rem -= total; prefix |= 1u << bit; }
    }
    union { unsigned u; float f; } cv; cv.u = prefix;
    float v0 = cv.f;
    int cle = 0;
    float mg = 3.4e38f;
#pragma unroll
    for (int s = 0; s < 20; ++s) {
        union { unsigned u; float f; } w; w.u = v[s];
        float f = w.f;
        cle += (f <= v0) ? 1 : 0;
        if (f > v0) mg = fminf(mg, f);
    }
#pragma unroll
    for (int o = 32; o > 0; o >>= 1) {
        cle += __shfl_down(cle, o, 64);
        mg = fminf(mg, __shfl_down(mg, o, 64));
    }
    if ((tid & 63) == 0) { red[tid >> 6] = cle; redf[tid >> 6] = mg; }
    __syncthreads();
    if (tid == 0) {
        int tc = 0; float tm = 3.4e38f;
#pragma unroll
        for (int w = 0; w < 8; ++w) { tc += red[w]; tm = fminf(tm, redf[w]); }
        float v1 = (tc >= 7501) ? v0 : tm;
        thr[b] = v0 + 0.25f * (v1 - v0);
    }
}

// ---------- K6: fp32 tiled GEMM (layer 1, K=16), fused L/R via blockIdx.z ----------
__global__ __launch_bounds__(256) void proj_gemm(const float* __restrict__ X,
                                                 const float* __restrict__ WL, const float* __restrict__ WR,
                                                 const float* __restrict__ biasL, const float* __restrict__ biasR,
                                                 float* __restrict__ outL, float* __restrict__ outR,
                                                 int K, int Nout) {
    __shared__ float As[16][65];
    __shared__ float Bs[16][128];
    const float* W = blockIdx.z ? WR : WL;
    const float* bias = blockIdx.z ? biasR : biasL;
    float* out = blockIdx.z ? outR : outL;
    int tid = threadIdx.x;
    int tm = tid & 15, tn = tid >> 4;
    int m0 = blockIdx.x * 64, n0 = blockIdx.y * 128;
    float acc[4][8];
#pragma unroll
    for (int r = 0; r < 4; ++r)
#pragma unroll
        for (int c = 0; c < 8; ++c) acc[r][c] = 0.f;
    for (int k0 = 0; k0 < K; k0 += 16) {
        for (int e = tid; e < 64 * 16; e += 256) {
            int kk = e & 15, mm = e >> 4;
            As[kk][mm] = X[(size_t)(m0 + mm) * K + k0 + kk];
        }
        for (int e = tid; e < 16 * 128; e += 256) {
            int nn = e & 127, kk = e >> 7;
            Bs[kk][nn] = W[(size_t)(k0 + kk) * Nout + n0 + nn];
        }
        __syncthreads();
#pragma unroll
        for (int kk = 0; kk < 16; ++kk) {
            float a[4], bb[8];
#pragma unroll
            for (int r = 0; r < 4; ++r) a[r] = As[kk][tm * 4 + r];
#pragma unroll
            for (int c = 0; c < 8; ++c) bb[c] = Bs[kk][tn * 8 + c];
#pragma unroll
            for (int r = 0; r < 4; ++r)
#pragma unroll
                for (int c = 0; c < 8; ++c) acc[r][c] += a[r] * bb[c];
        }
        __syncthreads();
    }
#pragma unroll
    for (int r = 0; r < 4; ++r)
#pragma unroll
        for (int c = 0; c < 8; ++c)
            out[(size_t)(m0 + tm * 4 + r) * Nout + n0 + tn * 8 + c] = acc[r][c] + bias[n0 + tn * 8 + c];
}

// ---------- K6d: bf16 MFMA GEMM out[M,N] = Xb[M,K] @ Wt[N,K]^T + bias, BK=64 ----------
__global__ __launch_bounds__(256) void mfma_proj(const short* __restrict__ Xb,
                                                 const short* __restrict__ WtL, const short* __restrict__ WtR,
                                                 const float* __restrict__ biasL, const float* __restrict__ biasR,
                                                 float* __restrict__ outL, float* __restrict__ outR,
                                                 int K, int N) {
    __shared__ short As[64 * 72];
    __shared__ short Bs[64 * 72];
    const short* Wt  = blockIdx.z ? WtR : WtL;
    const float* bias = blockIdx.z ? biasR : biasL;
    float* out = blockIdx.z ? outR : outL;
    int m0 = blockIdx.x * 64, n0 = blockIdx.y * 64;
    int tid = threadIdx.x;
    int row = tid >> 2, part = tid & 3;
    int lane = tid & 63, wave = tid >> 6;
    int wm = wave & 1, wn = wave >> 1;
    int quad = lane >> 4, l16 = lane & 15;
    f32x4 acc00 = {}, acc01 = {}, acc10 = {}, acc11 = {};
    const short* gA = Xb + (size_t)(m0 + row) * K + part * 16;
    const short* gB = Wt + (size_t)(n0 + row) * K + part * 16;
    short* sA = As + row * 72 + part * 16;
    short* sB = Bs + row * 72 + part * 16;
    const short* fA = As + (wm * 32 + l16) * 72 + quad * 8;
    const short* fB = Bs + (wn * 32 + l16) * 72 + quad * 8;
    for (int k0 = 0; k0 < K; k0 += 64) {
        *reinterpret_cast<s16x8*>(sA)     = *reinterpret_cast<const s16x8*>(gA + k0);
        *reinterpret_cast<s16x8*>(sA + 8) = *reinterpret_cast<const s16x8*>(gA + k0 + 8);
        *reinterpret_cast<s16x8*>(sB)     = *reinterpret_cast<const s16x8*>(gB + k0);
        *reinterpret_cast<s16x8*>(sB + 8) = *reinterpret_cast<const s16x8*>(gB + k0 + 8);
        __syncthreads();
#pragma unroll
        for (int ks = 0; ks < 2; ++ks) {
            s16x8 a0 = *reinterpret_cast<const s16x8*>(fA + ks * 32);
            s16x8 a1 = *reinterpret_cast<const s16x8*>(fA + ks * 32 + 16 * 72);
            s16x8 b0 = *reinterpret_cast<const s16x8*>(fB + ks * 32);
            s16x8 b1 = *reinterpret_cast<const s16x8*>(fB + ks * 32 + 16 * 72);
            acc00 = __builtin_amdgcn_mfma_f32_16x16x32_bf16(a0, b0, acc00, 0, 0, 0);
            acc01 = __builtin_amdgcn_mfma_f32_16x16x32_bf16(a0, b1, acc01, 0, 0, 0);
            acc10 = __builtin_amdgcn_mfma_f32_16x16x32_bf16(a1, b0, acc10, 0, 0, 0);
            acc11 = __builtin_amdgcn_mfma_f32_16x16x32_bf16(a1, b1, acc11, 0, 0, 0);
        }
        __syncthreads();
    }
#pragma unroll
    for (int tm = 0; tm < 2; ++tm)
#pragma unroll
        for (int tn = 0; tn < 2; ++tn) {
            const f32x4& a = tm == 0 ? (tn == 0 ? acc00 : acc01) : (tn == 0 ? acc10 : acc11);
            int mbase = m0 + wm * 32 + tm * 16 + quad * 4;
            int n = n0 + wn * 32 + tn * 16 + l16;
            float bv = bias[n];
#pragma unroll
            for (int r = 0; r < 4; ++r)
                out[(size_t)(mbase + r) * N + n] = a[r] + bv;
        }
}

// ---------- K7: fused GATv2 layer: scores + masked softmax + aggregation + GELU ----------
// grid (B*H, 100/NTILE), block 256.
// phase A (scores, lanes j=tid&127, cg=tid>>7 handles half the channels)
// phase B (softmax, 40 lanes: 4 per i-row) -> P in LDS
// phase C (out[i,c] = sum_j P[i,j]*xl[j,c], lane = channel, coalesced xl reads)
__global__ __launch_bounds__(256) void gat_fused(const float* __restrict__ xl, const float* __restrict__ xr,
                                                 const float* __restrict__ att, const float* __restrict__ adjsym,
                                                 const float* __restrict__ thr, const float* __restrict__ bias,
                                                 short* __restrict__ yout, float* __restrict__ pool_out,
                                                 int H, int C, int self_loop, int pool) {
    __shared__ float s_abs2[2][NTILE][104];
    __shared__ float dl2[2][104];
    __shared__ float p_lds[NTILE][104];
    __shared__ float s_xr[NTILE][256];
    int bh = blockIdx.x;
    int b = bh / H, h = bh % H;
    int i0 = blockIdx.y * NTILE;
    int tid = threadIdx.x;
    const float* atth = att + h * C;

    // stage the 10 xr rows (coalesced)
    for (int e = tid; e < NTILE * C; e += 256) {
        int i = e / C, c = e - i * C;
        s_xr[i][c] = xr[((size_t)(b * NROI + i0 + i) * H + h) * C + c];
    }
    __syncthreads();

    // ---- phase A ----
    {
        int j = tid & 127;
        int cg = tid >> 7;
        int Ch = C >> 1;
        int cbase = cg * Ch;
        const float* xlrow = xl + ((size_t)(b * NROI + (j < NROI ? j : 0)) * H + h) * C + cbase;
        const float* attp0 = atth + cbase;
        float acc[NTILE];
        float dl = 0.f;
#pragma unroll
        for (int i = 0; i < NTILE; ++i) acc[i] = 0.f;
        for (int cc = 0; cc < Ch; cc += 32) {
            float xlr[32];
#pragma unroll
            for (int t = 0; t < 32; t += 4) {
                float4 v = *reinterpret_cast<const float4*>(xlrow + cc + t);
                xlr[t] = v.x; xlr[t + 1] = v.y; xlr[t + 2] = v.z; xlr[t + 3] = v.w;
            }
            const float* attp = attp0 + cc;
#pragma unroll
            for (int t = 0; t < 32; ++t) dl += attp[t] * xlr[t];
#pragma unroll
            for (int i = 0; i < NTILE; ++i) {
                const float* xrp = &s_xr[i][cbase + cc];
                float s = 0.f;
#pragma unroll
                for (int t = 0; t < 32; t += 4) {
                    float4 xv = *reinterpret_cast<const float4*>(xrp + t);   // LDS broadcast b128
                    s += attp[t + 0] * fabsf(xlr[t + 0] + xv.x);
                    s += attp[t + 1] * fabsf(xlr[t + 1] + xv.y);
                    s += attp[t + 2] * fabsf(xlr[t + 2] + xv.z);
                    s += attp[t + 3] * fabsf(xlr[t + 3] + xv.w);
                }
                acc[i] += s;
            }
        }
        if (j < NROI) {
            dl2[cg][j] = dl;
#pragma unroll
            for (int i = 0; i < NTILE; ++i) s_abs2[cg][i][j] = acc[i];
        }
    }
    __syncthreads();

    // ---- phase B: softmax (4 lanes per row i) ----
    if (tid < NTILE * 4) {
        int i = tid >> 2, q = tid & 3;
        int gi = i0 + i;
        int c4 = C >> 2;
        const float* xrrow = xr + ((size_t)(b * NROI + gi) * H + h) * C + q * c4;
        const float* attq = atth + q * c4;
        float dr = 0.f;
        for (int c = 0; c < c4; ++c) dr += attq[c] * xrrow[c];
        dr += __shfl_xor(dr, 1, 64);
        dr += __shfl_xor(dr, 2, 64);
        float tb = thr[b];
        const float* arow = adjsym + (size_t)b * FLATD + gi * NROI + q * 25;
        float em[25];
        float mx = -3.0e38f;
#pragma unroll
        for (int k = 0; k < 25; ++k) {
            int jj = q * 25 + k;
            float e = 0.6f * (dl2[0][jj] + dl2[1][jj] + dr)
                    + 0.4f * (s_abs2[0][i][jj] + s_abs2[1][i][jj]);
            bool edge = (arow[k] > tb) || (self_loop && (jj == gi));
            float v = edge ? e : -1.0e9f;
            em[k] = v;
            mx = fmaxf(mx, v);
        }
        mx = fmaxf(mx, __shfl_xor(mx, 1, 64));
        mx = fmaxf(mx, __shfl_xor(mx, 2, 64));
        float sum = 0.f;
#pragma unroll
        for (int k = 0; k < 25; ++k) {
            em[k] = (em[k] > -0.5e9f) ? expf(em[k] - mx) : 0.f;
            sum += em[k];
        }
        sum += __shfl_xor(sum, 1, 64);
        sum += __shfl_xor(sum, 2, 64);
        float inv = (sum > 0.f) ? 1.0f / sum : 0.f;
#pragma unroll
        for (int k = 0; k < 25; ++k) p_lds[i][q * 25 + k] = em[k] * inv;
    }
    __syncthreads();

    // ---- phase C: aggregation ----
    for (int c = tid; c < C; c += 256) {
        float acc[NTILE];
#pragma unroll
        for (int i = 0; i < NTILE; ++i) acc[i] = 0.f;
        const float* xbase = xl + ((size_t)(b * NROI) * H + h) * C + c;
        size_t jstride = (size_t)H * C;
        for (int j0 = 0; j0 < NROI; j0 += 4) {
            float x0v = xbase[(j0 + 0) * jstride];
            float x1v = xbase[(j0 + 1) * jstride];
            float x2v = xbase[(j0 + 2) * jstride];
            float x3v = xbase[(j0 + 3) * jstride];
#pragma unroll
            for (int i = 0; i < NTILE; ++i) {
                float4 p = *reinterpret_cast<const float4*>(&p_lds[i][j0]);   // broadcast
                acc[i] += p.x * x0v + p.y * x1v + p.z * x2v + p.w * x3v;
            }
        }
        float bval = bias[h * C + c];
        if (pool) {
            float pacc = 0.f;
#pragma unroll
            for (int i = 0; i < NTILE; ++i) pacc += 0.01f * geluf(acc[i] + bval);
            atomicAdd(pool_out + b * 128 + c, pacc);
        } else {
#pragma unroll
            for (int i = 0; i < NTILE; ++i) {
                int gi = i0 + i;
                yout[((size_t)(b * NROI + gi) * H + h) * C + c] = f2bf(geluf(acc[i] + bval));
            }
        }
    }
}

// ---------- launcher ----------
extern "C" void kernel_launch(void* const* d_in, const int* in_sizes, int n_in,
                              void* d_out, int out_size, void* d_ws, size_t ws_size,
                              hipStream_t stream) {
    const float* A    = (const float*)d_in[0];
    const float* gbW  = (const float*)d_in[1];
    const float* gbb  = (const float*)d_in[2];
    const float* feW1 = (const float*)d_in[3];
    const float* feb1 = (const float*)d_in[4];
    const float* feW2 = (const float*)d_in[5];
    const float* feb2 = (const float*)d_in[6];
    const float* feg  = (const float*)d_in[7];
    const float* febt = (const float*)d_in[8];
    const float* Wl1  = (const float*)d_in[9];
    const float* bl1  = (const float*)d_in[10];
    const float* Wr1  = (const float*)d_in[11];
    const float* br1  = (const float*)d_in[12];
    const float* att1 = (const float*)d_in[13];
    const float* bias1= (const float*)d_in[14];
    const float* Wl2  = (const float*)d_in[15];
    const float* bl2  = (const float*)d_in[16];
    const float* Wr2  = (const float*)d_in[17];
    const float* br2  = (const float*)d_in[18];
    const float* att2 = (const float*)d_in[19];
    const float* bias2= (const float*)d_in[20];
    const float* Wl3  = (const float*)d_in[21];
    const float* bl3  = (const float*)d_in[22];
    const float* Wr3  = (const float*)d_in[23];
    const float* br3  = (const float*)d_in[24];
    const float* att3 = (const float*)d_in[25];
    const float* bias3= (const float*)d_in[26];

    float* ws = (float*)d_ws;
    float* adj   = ws + 0;          // 160000
    float* thr   = ws + 160000;     // 16
    float* bft   = ws + 160016;     // 3200
    float* x0    = ws + 163216;     // 25600
    float* xlbuf = ws + 188816;     // 1638400
    float* xrbuf = ws + 1827216;    // 1638400
    short* Xb    = (short*)(ws + 3465616);   // 819200 floats (1600x1024 bf16)
    short* Wt2l  = (short*)(ws + 4284816);   // 524288 floats
    short* Wt2r  = (short*)(ws + 4809104);
    short* Wt3l  = (short*)(ws + 5333392);   // 65536
    short* Wt3r  = (short*)(ws + 5398928);
    float* prep  = ws + 5464464;    // 25*160000 = 4,000,000  (end ~37.9 MB)

    hipMemsetAsync(d_out, 0, (size_t)out_size * sizeof(float), stream);

    gemm1_part<<<dim3(20, 25), 256, 0, stream>>>(A, gbW, prep);
    prep_w<<<2304, 256, 0, stream>>>(Wl2, Wr2, Wl3, Wr3, Wt2l, Wt2r, Wt3l, Wt3r);
    sym_stats<<<dim3(BATCH, 2), 256, 0, stream>>>(prep, gbb, adj, bft);
    quant_enh<<<20, 512, 0, stream>>>(adj, thr, bft, feW1, feb1, feW2, feb2, feg, febt, x0);

    // layer 1: H=8, C=128, no self loops (K=16 -> fp32 path)
    proj_gemm<<<dim3(25, 8, 2), 256, 0, stream>>>(x0, Wl1, Wr1, bl1, br1, xlbuf, xrbuf, 16, 1024);
    gat_fused<<<dim3(128, 10), 256, 0, stream>>>(xlbuf, xrbuf, att1, adj, thr, bias1, Xb, nullptr, 8, 128, 0, 0);

    // layer 2: H=4, C=256, self loops (MFMA path)
    mfma_proj<<<dim3(25, 16, 2), 256, 0, stream>>>(Xb, Wt2l, Wt2r, bl2, br2, xlbuf, xrbuf, 1024, 1024);
    gat_fused<<<dim3(64, 10), 256, 0, stream>>>(xlbuf, xrbuf, att2, adj, thr, bias2, Xb, nullptr, 4, 256, 1, 0);

    // layer 3: H=1, C=128, self loops (MFMA path), mean-pool into d_out
    mfma_proj<<<dim3(25, 2, 2), 256, 0, stream>>>(Xb, Wt3l, Wt3r, bl3, br3, xlbuf, xrbuf, 1024, 128);
    gat_fused<<<dim3(16, 10), 256, 0, stream>>>(xlbuf, xrbuf, att3, adj, thr, bias3, nullptr, (float*)d_out, 1, 128, 1, 1);
}

// Round 4
// 821.919 us; speedup vs baseline: 1.3526x; 1.1437x over previous
//
#include <hip/hip_runtime.h>
#include <cmath>

#define BATCH 16
#define NROI 100
#define FLATD 10000
#define NTILE 10

typedef __attribute__((ext_vector_type(8))) short s16x8;
typedef __attribute__((ext_vector_type(4))) short s16x4;
typedef __attribute__((ext_vector_type(4))) float f32x4;

// ---------- helpers ----------
__device__ __forceinline__ float sigmoidf(float x) { return 1.0f / (1.0f + expf(-x)); }
__device__ __forceinline__ float geluf(float x) { return 0.5f * x * (1.0f + erff(x * 0.70710678118654752f)); }
__device__ __forceinline__ short f2bf(float x) {
    union { float f; unsigned u; } v; v.f = x;
    unsigned r = v.u + 0x7FFF + ((v.u >> 16) & 1);
    return (short)(r >> 16);
}

// ---------- K1: fused big-GEMM partials + weight transpose/convert ----------
// blocks [0,500): gemm partials part[ky][16][10000] = A @ gbW slice
// blocks [500,1524): Wl2; [1524,2548): Wr2; [2548,2676): Wl3; [2676,2804): Wr3
__global__ __launch_bounds__(256) void gemm1_prep(const float* __restrict__ A, const float* __restrict__ W,
                                                  float* __restrict__ part,
                                                  const float* __restrict__ Wl2, const float* __restrict__ Wr2,
                                                  const float* __restrict__ Wl3, const float* __restrict__ Wr3,
                                                  short* __restrict__ Wt2l, short* __restrict__ Wt2r,
                                                  short* __restrict__ Wt3l, short* __restrict__ Wt3r) {
    __shared__ float sA[400][16];
    int bid = blockIdx.x;
    int tid = threadIdx.x;
    if (bid < 500) {
        // ---- gemm path ----
        int bx = bid % 20, ky = bid / 20;
        int k0 = ky * 400;
        for (int e = tid; e < 16 * 400; e += 256) {
            int m = e / 400, kk = e - m * 400;
            sA[kk][m] = A[(size_t)m * FLATD + k0 + kk];   // coalesced (kk fastest)
        }
        __syncthreads();
        int col = bx * 512 + tid * 2;
        if (col >= FLATD) return;
        float acc0[16], acc1[16];
#pragma unroll
        for (int m = 0; m < 16; ++m) { acc0[m] = 0.f; acc1[m] = 0.f; }
        const float* wp = W + (size_t)k0 * FLATD + col;
        for (int kk = 0; kk < 400; kk += 8) {
            float2 w[8];
#pragma unroll
            for (int u = 0; u < 8; ++u)
                w[u] = *reinterpret_cast<const float2*>(wp + (size_t)(kk + u) * FLATD);
#pragma unroll
            for (int u = 0; u < 8; ++u) {
                const float* a = sA[kk + u];              // broadcast ds_read_b128 x4
#pragma unroll
                for (int m = 0; m < 16; ++m) { acc0[m] += a[m] * w[u].x; acc1[m] += a[m] * w[u].y; }
            }
        }
        float* dst = part + (size_t)ky * 160000;
#pragma unroll
        for (int m = 0; m < 16; ++m) {
            float2 o; o.x = acc0[m]; o.y = acc1[m];
            *reinterpret_cast<float2*>(dst + (size_t)m * FLATD + col) = o;
        }
        return;
    }
    // ---- weight convert path (backfills while gemm runs) ----
    float (*t)[33] = (float(*)[33])&sA[0][0];
    int r = bid - 500;
    const float* in; short* out; int N, xb, yb;
    if (r < 1024)      { in = Wl2; out = Wt2l; N = 1024; xb = r & 31; yb = r >> 5; }
    else if (r < 2048) { r -= 1024; in = Wr2; out = Wt2r; N = 1024; xb = r & 31; yb = r >> 5; }
    else if (r < 2176) { r -= 2048; in = Wl3; out = Wt3l; N = 128;  xb = r & 3;  yb = r >> 2; }
    else               { r -= 2176; in = Wr3; out = Wt3r; N = 128;  xb = r & 3;  yb = r >> 2; }
    int n0 = xb * 32, k0 = yb * 32;
    int tx = tid & 31, ty = tid >> 5;
#pragma unroll
    for (int i = 0; i < 32; i += 8)
        t[ty + i][tx] = in[(size_t)(k0 + ty + i) * N + n0 + tx];
    __syncthreads();
#pragma unroll
    for (int i = 0; i < 32; i += 8)
        out[(size_t)(n0 + ty + i) * 1024 + k0 + tx] = f2bf(t[tx][ty + i]);
}

// ---------- K2: fused per-sample: partial reduce + symmetrize + sigmoid + stats
//                + exact 0.75-quantile (radix) + feature enhancer ----------
// grid 16 (one block per batch sample), block 1024
__global__ __launch_bounds__(1024) void sym_quant_enh(const float* __restrict__ part, const float* __restrict__ gbb,
                                                      float* __restrict__ adjsym, float* __restrict__ thr,
                                                      const float* __restrict__ W1, const float* __restrict__ b1,
                                                      const float* __restrict__ W2, const float* __restrict__ b2,
                                                      const float* __restrict__ g, const float* __restrict__ beta,
                                                      float* __restrict__ x0) {
    __shared__ float s_adj[NROI][NROI + 1];   // stride 101: conflict-free transpose
    __shared__ int redi[16];
    __shared__ float redf[16];
    __shared__ float m_l[NROI], s_l[NROI];
    int b = blockIdx.x;
    int tid = threadIdx.x;

    // step 1: reduce 25 partials + bias + sigmoid -> LDS
    float sig[10];
#pragma unroll
    for (int s = 0; s < 10; ++s) {
        int e = s * 1024 + tid;
        if (e < FLATD) {
            const float* pp = part + (size_t)b * FLATD + e;
            float acc = gbb[e];
#pragma unroll
            for (int p = 0; p < 25; ++p) acc += pp[(size_t)p * 160000];
            sig[s] = sigmoidf(acc);
            s_adj[e / NROI][e % NROI] = sig[s];
        }
    }
    __syncthreads();

    // step 2: symmetrize via LDS transpose -> regs + global adjsym
    unsigned v[10];
#pragma unroll
    for (int s = 0; s < 10; ++s) {
        int e = s * 1024 + tid;
        if (e < FLATD) {
            int i = e / NROI, j = e - i * NROI;
            float w = 0.5f * (sig[s] + s_adj[j][i]);
            union { float f; unsigned u; } cv; cv.f = w;
            v[s] = cv.u;
            adjsym[(size_t)b * FLATD + e] = w;
        } else v[s] = 0x7F800000u;   // +inf pad (all vals in (0,1))
    }
    __syncthreads();

    // step 3: write symmetrized values back to LDS
#pragma unroll
    for (int s = 0; s < 10; ++s) {
        int e = s * 1024 + tid;
        if (e < FLATD) {
            union { unsigned u; float f; } cv; cv.u = v[s];
            s_adj[e / NROI][e - (e / NROI) * NROI] = cv.f;
        }
    }
    __syncthreads();

    // step 4: row stats (threads 0..99; stride-101 reads are conflict-free)
    if (tid < NROI) {
        float sum = 0.f, sumsq = 0.f;
        for (int j = 0; j < NROI; ++j) { float w = s_adj[tid][j]; sum += w; sumsq += w * w; }
        float mean = sum * 0.01f;
        float var = fmaxf((sumsq - sum * sum * 0.01f) * (1.0f / 99.0f), 0.f);
        m_l[tid] = mean;
        s_l[tid] = sqrtf(var) + 1e-6f;
    }
    __syncthreads();

    // step 5: radix-select rank 7499 (ascending) over the 10000 reg-held values
    int rem = 7499;
    unsigned prefix = 0;
    for (int bit = 30; bit >= 0; --bit) {
        unsigned pshift = prefix >> (bit + 1);
        int c = 0;
#pragma unroll
        for (int s = 0; s < 10; ++s) {
            unsigned x = v[s];
            c += (((x >> (bit + 1)) == pshift) && (((x >> bit) & 1u) == 0u)) ? 1 : 0;
        }
#pragma unroll
        for (int o = 32; o > 0; o >>= 1) c += __shfl_down(c, o, 64);
        if ((tid & 63) == 0) redi[tid >> 6] = c;
        __syncthreads();
        int total = 0;
#pragma unroll
        for (int w = 0; w < 16; ++w) total += redi[w];
        __syncthreads();
        if (rem >= total) { rem -= total; prefix |= 1u << bit; }
    }
    union { unsigned u; float f; } cv0; cv0.u = prefix;
    float v0 = cv0.f;

    // step 6: tie-aware rank-7500 via count(<=v0) and min(>v0)
    int cle = 0;
    float mg = 3.4e38f;
#pragma unroll
    for (int s = 0; s < 10; ++s) {
        union { unsigned u; float f; } w; w.u = v[s];
        float f = w.f;
        cle += (f <= v0) ? 1 : 0;
        if (f > v0) mg = fminf(mg, f);
    }
#pragma unroll
    for (int o = 32; o > 0; o >>= 1) {
        cle += __shfl_down(cle, o, 64);
        mg = fminf(mg, __shfl_down(mg, o, 64));
    }
    if ((tid & 63) == 0) { redi[tid >> 6] = cle; redf[tid >> 6] = mg; }
    __syncthreads();
    if (tid == 0) {
        int tc = 0; float tm = 3.4e38f;
#pragma unroll
        for (int w = 0; w < 16; ++w) { tc += redi[w]; tm = fminf(tm, redf[w]); }
        float v1 = (tc >= 7501) ? v0 : tm;
        thr[b] = v0 + 0.25f * (v1 - v0);
    }

    // step 7: feature enhancer + LayerNorm for this sample's 100 nodes
    if (tid < NROI) {
        float f0 = m_l[tid], f1 = s_l[tid];
        float h8[8];
#pragma unroll
        for (int u = 0; u < 8; ++u) h8[u] = geluf(W1[u] * f0 + W1[8 + u] * f1 + b1[u]);
        float o[16];
        float mu = 0.f;
#pragma unroll
        for (int vv = 0; vv < 16; ++vv) {
            float t2 = b2[vv];
#pragma unroll
            for (int u = 0; u < 8; ++u) t2 += h8[u] * W2[u * 16 + vv];
            o[vv] = t2; mu += t2;
        }
        mu *= (1.0f / 16.0f);
        float var = 0.f;
#pragma unroll
        for (int vv = 0; vv < 16; ++vv) { float d = o[vv] - mu; var += d * d; }
        var *= (1.0f / 16.0f);
        float inv = rsqrtf(var + 1e-5f);
        int idx = b * NROI + tid;
#pragma unroll
        for (int vv = 0; vv < 16; ++vv) x0[idx * 16 + vv] = (o[vv] - mu) * inv * g[vv] + beta[vv];
    }
}

// ---------- K3: fp32 tiled GEMM (layer 1, K=16), fused L/R via blockIdx.z ----------
__global__ __launch_bounds__(256) void proj_gemm(const float* __restrict__ X,
                                                 const float* __restrict__ WL, const float* __restrict__ WR,
                                                 const float* __restrict__ biasL, const float* __restrict__ biasR,
                                                 float* __restrict__ outL, float* __restrict__ outR,
                                                 int K, int Nout) {
    __shared__ float As[16][65];
    __shared__ float Bs[16][128];
    const float* W = blockIdx.z ? WR : WL;
    const float* bias = blockIdx.z ? biasR : biasL;
    float* out = blockIdx.z ? outR : outL;
    int tid = threadIdx.x;
    int tm = tid & 15, tn = tid >> 4;
    int m0 = blockIdx.x * 64, n0 = blockIdx.y * 128;
    float acc[4][8];
#pragma unroll
    for (int r = 0; r < 4; ++r)
#pragma unroll
        for (int c = 0; c < 8; ++c) acc[r][c] = 0.f;
    for (int k0 = 0; k0 < K; k0 += 16) {
        for (int e = tid; e < 64 * 16; e += 256) {
            int kk = e & 15, mm = e >> 4;
            As[kk][mm] = X[(size_t)(m0 + mm) * K + k0 + kk];
        }
        for (int e = tid; e < 16 * 128; e += 256) {
            int nn = e & 127, kk = e >> 7;
            Bs[kk][nn] = W[(size_t)(k0 + kk) * Nout + n0 + nn];
        }
        __syncthreads();
#pragma unroll
        for (int kk = 0; kk < 16; ++kk) {
            float a[4], bb[8];
#pragma unroll
            for (int r = 0; r < 4; ++r) a[r] = As[kk][tm * 4 + r];
#pragma unroll
            for (int c = 0; c < 8; ++c) bb[c] = Bs[kk][tn * 8 + c];
#pragma unroll
            for (int r = 0; r < 4; ++r)
#pragma unroll
                for (int c = 0; c < 8; ++c) acc[r][c] += a[r] * bb[c];
        }
        __syncthreads();
    }
#pragma unroll
    for (int r = 0; r < 4; ++r)
#pragma unroll
        for (int c = 0; c < 8; ++c)
            out[(size_t)(m0 + tm * 4 + r) * Nout + n0 + tn * 8 + c] = acc[r][c] + bias[n0 + tn * 8 + c];
}

// ---------- K4: bf16 MFMA GEMM out[M,N] = Xb[M,K] @ Wt[N,K]^T + bias, BK=64 ----------
__global__ __launch_bounds__(256) void mfma_proj(const short* __restrict__ Xb,
                                                 const short* __restrict__ WtL, const short* __restrict__ WtR,
                                                 const float* __restrict__ biasL, const float* __restrict__ biasR,
                                                 float* __restrict__ outL, float* __restrict__ outR,
                                                 int K, int N) {
    __shared__ short As[64 * 72];
    __shared__ short Bs[64 * 72];
    const short* Wt  = blockIdx.z ? WtR : WtL;
    const float* bias = blockIdx.z ? biasR : biasL;
    float* out = blockIdx.z ? outR : outL;
    int m0 = blockIdx.x * 64, n0 = blockIdx.y * 64;
    int tid = threadIdx.x;
    int row = tid >> 2, part = tid & 3;
    int lane = tid & 63, wave = tid >> 6;
    int wm = wave & 1, wn = wave >> 1;
    int quad = lane >> 4, l16 = lane & 15;
    f32x4 acc00 = {}, acc01 = {}, acc10 = {}, acc11 = {};
    const short* gA = Xb + (size_t)(m0 + row) * K + part * 16;
    const short* gB = Wt + (size_t)(n0 + row) * K + part * 16;
    short* sA = As + row * 72 + part * 16;
    short* sB = Bs + row * 72 + part * 16;
    const short* fA = As + (wm * 32 + l16) * 72 + quad * 8;
    const short* fB = Bs + (wn * 32 + l16) * 72 + quad * 8;
    for (int k0 = 0; k0 < K; k0 += 64) {
        *reinterpret_cast<s16x8*>(sA)     = *reinterpret_cast<const s16x8*>(gA + k0);
        *reinterpret_cast<s16x8*>(sA + 8) = *reinterpret_cast<const s16x8*>(gA + k0 + 8);
        *reinterpret_cast<s16x8*>(sB)     = *reinterpret_cast<const s16x8*>(gB + k0);
        *reinterpret_cast<s16x8*>(sB + 8) = *reinterpret_cast<const s16x8*>(gB + k0 + 8);
        __syncthreads();
#pragma unroll
        for (int ks = 0; ks < 2; ++ks) {
            s16x8 a0 = *reinterpret_cast<const s16x8*>(fA + ks * 32);
            s16x8 a1 = *reinterpret_cast<const s16x8*>(fA + ks * 32 + 16 * 72);
            s16x8 b0 = *reinterpret_cast<const s16x8*>(fB + ks * 32);
            s16x8 b1 = *reinterpret_cast<const s16x8*>(fB + ks * 32 + 16 * 72);
            acc00 = __builtin_amdgcn_mfma_f32_16x16x32_bf16(a0, b0, acc00, 0, 0, 0);
            acc01 = __builtin_amdgcn_mfma_f32_16x16x32_bf16(a0, b1, acc01, 0, 0, 0);
            acc10 = __builtin_amdgcn_mfma_f32_16x16x32_bf16(a1, b0, acc10, 0, 0, 0);
            acc11 = __builtin_amdgcn_mfma_f32_16x16x32_bf16(a1, b1, acc11, 0, 0, 0);
        }
        __syncthreads();
    }
#pragma unroll
    for (int tm = 0; tm < 2; ++tm)
#pragma unroll
        for (int tn = 0; tn < 2; ++tn) {
            const f32x4& a = tm == 0 ? (tn == 0 ? acc00 : acc01) : (tn == 0 ? acc10 : acc11);
            int mbase = m0 + wm * 32 + tm * 16 + quad * 4;
            int n = n0 + wn * 32 + tn * 16 + l16;
            float bv = bias[n];
#pragma unroll
            for (int r = 0; r < 4; ++r)
                out[(size_t)(mbase + r) * N + n] = a[r] + bv;
        }
}

// ---------- K5: fused GATv2 layer: scores + masked softmax + aggregation + GELU ----------
__global__ __launch_bounds__(256) void gat_fused(const float* __restrict__ xl, const float* __restrict__ xr,
                                                 const float* __restrict__ att, const float* __restrict__ adjsym,
                                                 const float* __restrict__ thr, const float* __restrict__ bias,
                                                 short* __restrict__ yout, float* __restrict__ pool_out,
                                                 int H, int C, int self_loop, int pool) {
    __shared__ float s_abs2[2][NTILE][104];
    __shared__ float dl2[2][104];
    __shared__ float p_lds[NTILE][104];
    __shared__ float s_xr[NTILE][256];
    int bh = blockIdx.x;
    int b = bh / H, h = bh % H;
    int i0 = blockIdx.y * NTILE;
    int tid = threadIdx.x;
    const float* atth = att + h * C;

    for (int e = tid; e < NTILE * C; e += 256) {
        int i = e / C, c = e - i * C;
        s_xr[i][c] = xr[((size_t)(b * NROI + i0 + i) * H + h) * C + c];
    }
    __syncthreads();

    // ---- phase A ----
    {
        int j = tid & 127;
        int cg = tid >> 7;
        int Ch = C >> 1;
        int cbase = cg * Ch;
        const float* xlrow = xl + ((size_t)(b * NROI + (j < NROI ? j : 0)) * H + h) * C + cbase;
        const float* attp0 = atth + cbase;
        float acc[NTILE];
        float dl = 0.f;
#pragma unroll
        for (int i = 0; i < NTILE; ++i) acc[i] = 0.f;
        for (int cc = 0; cc < Ch; cc += 32) {
            float xlr[32];
#pragma unroll
            for (int t = 0; t < 32; t += 4) {
                float4 v = *reinterpret_cast<const float4*>(xlrow + cc + t);
                xlr[t] = v.x; xlr[t + 1] = v.y; xlr[t + 2] = v.z; xlr[t + 3] = v.w;
            }
            const float* attp = attp0 + cc;
#pragma unroll
            for (int t = 0; t < 32; ++t) dl += attp[t] * xlr[t];
#pragma unroll
            for (int i = 0; i < NTILE; ++i) {
                const float* xrp = &s_xr[i][cbase + cc];
                float s = 0.f;
#pragma unroll
                for (int t = 0; t < 32; t += 4) {
                    float4 xv = *reinterpret_cast<const float4*>(xrp + t);
                    s += attp[t + 0] * fabsf(xlr[t + 0] + xv.x);
                    s += attp[t + 1] * fabsf(xlr[t + 1] + xv.y);
                    s += attp[t + 2] * fabsf(xlr[t + 2] + xv.z);
                    s += attp[t + 3] * fabsf(xlr[t + 3] + xv.w);
                }
                acc[i] += s;
            }
        }
        if (j < NROI) {
            dl2[cg][j] = dl;
#pragma unroll
            for (int i = 0; i < NTILE; ++i) s_abs2[cg][i][j] = acc[i];
        }
    }
    __syncthreads();

    // ---- phase B: softmax (4 lanes per row i) ----
    if (tid < NTILE * 4) {
        int i = tid >> 2, q = tid & 3;
        int gi = i0 + i;
        int c4 = C >> 2;
        const float* xrrow = xr + ((size_t)(b * NROI + gi) * H + h) * C + q * c4;
        const float* attq = atth + q * c4;
        float dr = 0.f;
        for (int c = 0; c < c4; ++c) dr += attq[c] * xrrow[c];
        dr += __shfl_xor(dr, 1, 64);
        dr += __shfl_xor(dr, 2, 64);
        float tb = thr[b];
        const float* arow = adjsym + (size_t)b * FLATD + gi * NROI + q * 25;
        float em[25];
        float mx = -3.0e38f;
#pragma unroll
        for (int k = 0; k < 25; ++k) {
            int jj = q * 25 + k;
            float e = 0.6f * (dl2[0][jj] + dl2[1][jj] + dr)
                    + 0.4f * (s_abs2[0][i][jj] + s_abs2[1][i][jj]);
            bool edge = (arow[k] > tb) || (self_loop && (jj == gi));
            float v = edge ? e : -1.0e9f;
            em[k] = v;
            mx = fmaxf(mx, v);
        }
        mx = fmaxf(mx, __shfl_xor(mx, 1, 64));
        mx = fmaxf(mx, __shfl_xor(mx, 2, 64));
        float sum = 0.f;
#pragma unroll
        for (int k = 0; k < 25; ++k) {
            em[k] = (em[k] > -0.5e9f) ? expf(em[k] - mx) : 0.f;
            sum += em[k];
        }
        sum += __shfl_xor(sum, 1, 64);
        sum += __shfl_xor(sum, 2, 64);
        float inv = (sum > 0.f) ? 1.0f / sum : 0.f;
#pragma unroll
        for (int k = 0; k < 25; ++k) p_lds[i][q * 25 + k] = em[k] * inv;
    }
    __syncthreads();

    // ---- phase C: aggregation ----
    for (int c = tid; c < C; c += 256) {
        float acc[NTILE];
#pragma unroll
        for (int i = 0; i < NTILE; ++i) acc[i] = 0.f;
        const float* xbase = xl + ((size_t)(b * NROI) * H + h) * C + c;
        size_t jstride = (size_t)H * C;
        for (int j0 = 0; j0 < NROI; j0 += 4) {
            float x0v = xbase[(j0 + 0) * jstride];
            float x1v = xbase[(j0 + 1) * jstride];
            float x2v = xbase[(j0 + 2) * jstride];
            float x3v = xbase[(j0 + 3) * jstride];
#pragma unroll
            for (int i = 0; i < NTILE; ++i) {
                float4 p = *reinterpret_cast<const float4*>(&p_lds[i][j0]);
                acc[i] += p.x * x0v + p.y * x1v + p.z * x2v + p.w * x3v;
            }
        }
        float bval = bias[h * C + c];
        if (pool) {
            float pacc = 0.f;
#pragma unroll
            for (int i = 0; i < NTILE; ++i) pacc += 0.01f * geluf(acc[i] + bval);
            atomicAdd(pool_out + b * 128 + c, pacc);
        } else {
#pragma unroll
            for (int i = 0; i < NTILE; ++i) {
                int gi = i0 + i;
                yout[((size_t)(b * NROI + gi) * H + h) * C + c] = f2bf(geluf(acc[i] + bval));
            }
        }
    }
}

// ---------- launcher ----------
extern "C" void kernel_launch(void* const* d_in, const int* in_sizes, int n_in,
                              void* d_out, int out_size, void* d_ws, size_t ws_size,
                              hipStream_t stream) {
    const float* A    = (const float*)d_in[0];
    const float* gbW  = (const float*)d_in[1];
    const float* gbb  = (const float*)d_in[2];
    const float* feW1 = (const float*)d_in[3];
    const float* feb1 = (const float*)d_in[4];
    const float* feW2 = (const float*)d_in[5];
    const float* feb2 = (const float*)d_in[6];
    const float* feg  = (const float*)d_in[7];
    const float* febt = (const float*)d_in[8];
    const float* Wl1  = (const float*)d_in[9];
    const float* bl1  = (const float*)d_in[10];
    const float* Wr1  = (const float*)d_in[11];
    const float* br1  = (const float*)d_in[12];
    const float* att1 = (const float*)d_in[13];
    const float* bias1= (const float*)d_in[14];
    const float* Wl2  = (const float*)d_in[15];
    const float* bl2  = (const float*)d_in[16];
    const float* Wr2  = (const float*)d_in[17];
    const float* br2  = (const float*)d_in[18];
    const float* att2 = (const float*)d_in[19];
    const float* bias2= (const float*)d_in[20];
    const float* Wl3  = (const float*)d_in[21];
    const float* bl3  = (const float*)d_in[22];
    const float* Wr3  = (const float*)d_in[23];
    const float* br3  = (const float*)d_in[24];
    const float* att3 = (const float*)d_in[25];
    const float* bias3= (const float*)d_in[26];

    float* ws = (float*)d_ws;
    float* adj   = ws + 0;          // 160000
    float* thr   = ws + 160000;     // 16
    float* x0    = ws + 160016;     // 25600
    float* xlbuf = ws + 185616;     // 1638400
    float* xrbuf = ws + 1824016;    // 1638400
    short* Xb    = (short*)(ws + 3462416);   // 819200 floats (1600x1024 bf16)
    short* Wt2l  = (short*)(ws + 4281616);   // 524288 floats
    short* Wt2r  = (short*)(ws + 4805904);
    short* Wt3l  = (short*)(ws + 5330192);   // 65536
    short* Wt3r  = (short*)(ws + 5395728);
    float* prep  = ws + 5461264;    // 25*160000 = 4,000,000  (end ~37.8 MB)

    hipMemsetAsync(d_out, 0, (size_t)out_size * sizeof(float), stream);

    gemm1_prep<<<2804, 256, 0, stream>>>(A, gbW, prep, Wl2, Wr2, Wl3, Wr3, Wt2l, Wt2r, Wt3l, Wt3r);
    sym_quant_enh<<<BATCH, 1024, 0, stream>>>(prep, gbb, adj, thr,
                                              feW1, feb1, feW2, feb2, feg, febt, x0);

    // layer 1: H=8, C=128, no self loops (K=16 -> fp32 path)
    proj_gemm<<<dim3(25, 8, 2), 256, 0, stream>>>(x0, Wl1, Wr1, bl1, br1, xlbuf, xrbuf, 16, 1024);
    gat_fused<<<dim3(128, 10), 256, 0, stream>>>(xlbuf, xrbuf, att1, adj, thr, bias1, Xb, nullptr, 8, 128, 0, 0);

    // layer 2: H=4, C=256, self loops (MFMA path)
    mfma_proj<<<dim3(25, 16, 2), 256, 0, stream>>>(Xb, Wt2l, Wt2r, bl2, br2, xlbuf, xrbuf, 1024, 1024);
    gat_fused<<<dim3(64, 10), 256, 0, stream>>>(xlbuf, xrbuf, att2, adj, thr, bias2, Xb, nullptr, 4, 256, 1, 0);

    // layer 3: H=1, C=128, self loops (MFMA path), mean-pool into d_out
    mfma_proj<<<dim3(25, 2, 2), 256, 0, stream>>>(Xb, Wt3l, Wt3r, bl3, br3, xlbuf, xrbuf, 1024, 128);
    gat_fused<<<dim3(16, 10), 256, 0, stream>>>(xlbuf, xrbuf, att3, adj, thr, bias3, nullptr, (float*)d_out, 1, 128, 1, 1);
}